// Round 1
// baseline (686.769 us; speedup 1.0000x reference)
//
#include <hip/hip_runtime.h>
#include <math.h>

#define N_NODES 100000
#define N_EDGES 3200000
#define EPRIME  (N_EDGES + N_NODES)
#define NFEAT   512
#define HID     16
#define NCLS    10

// ---------------------------------------------------------------------------
// h = relu(x @ W1 + b1).  One wave per row; W1 (512x16) lives in registers:
// lane covers k in [8*lane, 8*lane+8), 8x16 = 128 VGPRs of W1 per lane.
// Halving-butterfly reduce: 17 shuffles instead of 96.
// ---------------------------------------------------------------------------
__global__ __launch_bounds__(256) void k_gemm_relu(const float* __restrict__ x,
                                                   const float* __restrict__ W1,
                                                   const float* __restrict__ b1,
                                                   float* __restrict__ h) {
  const int lane   = threadIdx.x & 63;
  const int wid    = blockIdx.x * (blockDim.x >> 6) + (threadIdx.x >> 6);
  const int nwaves = gridDim.x * (blockDim.x >> 6);

  float4 w[8][4];
#pragma unroll
  for (int kk = 0; kk < 8; ++kk)
#pragma unroll
    for (int j = 0; j < 4; ++j)
      w[kk][j] = *reinterpret_cast<const float4*>(W1 + (lane * 8 + kk) * 16 + j * 4);

  const int outCol = (lane >> 2) & 15;
  const float bias = b1[outCol];

  for (int row = wid; row < N_NODES; row += nwaves) {
    const float4 xv0 = *reinterpret_cast<const float4*>(x + (size_t)row * NFEAT + lane * 8);
    const float4 xv1 = *reinterpret_cast<const float4*>(x + (size_t)row * NFEAT + lane * 8 + 4);
    float xs[8] = {xv0.x, xv0.y, xv0.z, xv0.w, xv1.x, xv1.y, xv1.z, xv1.w};

    float acc[16];
#pragma unroll
    for (int j = 0; j < 16; ++j) acc[j] = 0.f;

#pragma unroll
    for (int kk = 0; kk < 8; ++kk) {
      const float xv = xs[kk];
#pragma unroll
      for (int j4 = 0; j4 < 4; ++j4) {
        acc[j4 * 4 + 0] = fmaf(xv, w[kk][j4].x, acc[j4 * 4 + 0]);
        acc[j4 * 4 + 1] = fmaf(xv, w[kk][j4].y, acc[j4 * 4 + 1]);
        acc[j4 * 4 + 2] = fmaf(xv, w[kk][j4].z, acc[j4 * 4 + 2]);
        acc[j4 * 4 + 3] = fmaf(xv, w[kk][j4].w, acc[j4 * 4 + 3]);
      }
    }

    // Halving reduce across 64 lanes: lane l ends holding col (l>>2)&15.
#pragma unroll
    for (int i = 0; i < 8; ++i) {
      float send = (lane & 32) ? acc[i] : acc[i + 8];
      float r = __shfl_xor(send, 32);
      acc[i] = ((lane & 32) ? acc[i + 8] : acc[i]) + r;
    }
#pragma unroll
    for (int i = 0; i < 4; ++i) {
      float send = (lane & 16) ? acc[i] : acc[i + 4];
      float r = __shfl_xor(send, 16);
      acc[i] = ((lane & 16) ? acc[i + 4] : acc[i]) + r;
    }
#pragma unroll
    for (int i = 0; i < 2; ++i) {
      float send = (lane & 8) ? acc[i] : acc[i + 2];
      float r = __shfl_xor(send, 8);
      acc[i] = ((lane & 8) ? acc[i + 2] : acc[i]) + r;
    }
    {
      float send = (lane & 4) ? acc[0] : acc[1];
      float r = __shfl_xor(send, 4);
      acc[0] = ((lane & 4) ? acc[1] : acc[0]) + r;
    }
    acc[0] += __shfl_xor(acc[0], 2);
    acc[0] += __shfl_xor(acc[0], 1);

    if ((lane & 3) == 0)
      h[(size_t)row * HID + outCol] = fmaxf(acc[0] + bias, 0.f);
  }
}

// ---------------------------------------------------------------------------
// CSR build: count -> scan (3 kernels) -> fill.  Edges include self-loops:
// e < E: (src,dst) = (ei[e], ei[E+e]); e >= E: src = dst = e - E.
// ---------------------------------------------------------------------------
__global__ void k_count(const int* __restrict__ ei, int* __restrict__ counts) {
  int e = blockIdx.x * blockDim.x + threadIdx.x;
  if (e >= EPRIME) return;
  int d = (e < N_EDGES) ? ei[N_EDGES + e] : (e - N_EDGES);
  atomicAdd(&counts[d], 1);
}

__global__ void k_scan1(const int* __restrict__ counts, int* __restrict__ offs,
                        int* __restrict__ bsums) {
  __shared__ int s[1024];
  int g = blockIdx.x * 1024 + threadIdx.x;
  int v = (g < N_NODES) ? counts[g] : 0;
  s[threadIdx.x] = v;
  __syncthreads();
  for (int d = 1; d < 1024; d <<= 1) {
    int t = (threadIdx.x >= d) ? s[threadIdx.x - d] : 0;
    __syncthreads();
    s[threadIdx.x] += t;
    __syncthreads();
  }
  if (g < N_NODES) offs[g] = s[threadIdx.x] - v;  // exclusive (local)
  if (threadIdx.x == 1023) bsums[blockIdx.x] = s[1023];
}

__global__ void k_scan2(int* __restrict__ bsums, int nb) {
  __shared__ int s[128];
  int v = (threadIdx.x < nb) ? bsums[threadIdx.x] : 0;
  s[threadIdx.x] = v;
  __syncthreads();
  for (int d = 1; d < 128; d <<= 1) {
    int t = (threadIdx.x >= d) ? s[threadIdx.x - d] : 0;
    __syncthreads();
    s[threadIdx.x] += t;
    __syncthreads();
  }
  if (threadIdx.x < nb) bsums[threadIdx.x] = s[threadIdx.x] - v;  // exclusive
}

__global__ void k_scan3(int* __restrict__ offs, const int* __restrict__ bsums,
                        int* __restrict__ cursor) {
  int g = blockIdx.x * blockDim.x + threadIdx.x;
  if (g < N_NODES) {
    int o = offs[g] + bsums[g >> 10];
    offs[g] = o;
    cursor[g] = o;
  }
  if (g == 0) offs[N_NODES] = EPRIME;
}

__global__ void k_fill(const int* __restrict__ ei, int* __restrict__ cursor,
                       int* __restrict__ csr) {
  int e = blockIdx.x * blockDim.x + threadIdx.x;
  if (e >= EPRIME) return;
  int s, d;
  if (e < N_EDGES) { s = ei[e]; d = ei[N_EDGES + e]; }
  else             { s = d = e - N_EDGES; }
  int pos = atomicAdd(&cursor[d], 1);
  csr[pos] = s;
}

// ---------------------------------------------------------------------------
// hn = h / max(||h||, 1e-12); norms[n] = ||h[n]||.  16 lanes per row.
// ---------------------------------------------------------------------------
__global__ void k_norm(const float* __restrict__ h, float* __restrict__ hn,
                       float* __restrict__ norms) {
  int t = blockIdx.x * blockDim.x + threadIdx.x;
  if (t >= N_NODES * HID) return;
  float v = h[t];
  float ss = v * v;
  ss += __shfl_xor(ss, 1);
  ss += __shfl_xor(ss, 2);
  ss += __shfl_xor(ss, 4);
  ss += __shfl_xor(ss, 8);
  float nrm = sqrtf(ss);
  float inv = 1.0f / fmaxf(nrm, 1e-12f);
  hn[t] = v * inv;
  if ((t & 15) == 0) norms[t >> 4] = nrm;
}

// ---------------------------------------------------------------------------
// Pull-mode AGNN conv: per dst node, iterate its CSR edges.
// ea = exp(beta * dot(hn[src], hn[dst])); out = (sum ea*norm_src*hn[src]) / sum ea.
// No fp atomics, denominator local.  h[src] == norms[src]*hn[src].
// ---------------------------------------------------------------------------
__global__ void k_pull(const float* __restrict__ hn, const float* __restrict__ norms,
                       const int* __restrict__ offs, const int* __restrict__ csr,
                       const float* __restrict__ beta_ptr, float* __restrict__ hout) {
  int n = blockIdx.x * blockDim.x + threadIdx.x;
  if (n >= N_NODES) return;
  const float beta = beta_ptr ? beta_ptr[0] : 1.0f;

  const float4* qp = reinterpret_cast<const float4*>(hn + (size_t)n * HID);
  const float4 q0 = qp[0], q1 = qp[1], q2 = qp[2], q3 = qp[3];

  const int s = offs[n], e = offs[n + 1];
  float den = 0.f;
  float4 a0 = {0,0,0,0}, a1 = {0,0,0,0}, a2 = {0,0,0,0}, a3 = {0,0,0,0};

  for (int i = s; i < e; ++i) {
    const int src = csr[i];
    const float4* sp = reinterpret_cast<const float4*>(hn + (size_t)src * HID);
    const float4 v0 = sp[0], v1 = sp[1], v2 = sp[2], v3 = sp[3];
    float dot = q0.x * v0.x + q0.y * v0.y + q0.z * v0.z + q0.w * v0.w;
    dot += q1.x * v1.x + q1.y * v1.y + q1.z * v1.z + q1.w * v1.w;
    dot += q2.x * v2.x + q2.y * v2.y + q2.z * v2.z + q2.w * v2.w;
    dot += q3.x * v3.x + q3.y * v3.y + q3.z * v3.z + q3.w * v3.w;
    const float t = __expf(beta * dot);
    den += t;
    const float wgt = t * norms[src];
    a0.x += wgt * v0.x; a0.y += wgt * v0.y; a0.z += wgt * v0.z; a0.w += wgt * v0.w;
    a1.x += wgt * v1.x; a1.y += wgt * v1.y; a1.z += wgt * v1.z; a1.w += wgt * v1.w;
    a2.x += wgt * v2.x; a2.y += wgt * v2.y; a2.z += wgt * v2.z; a2.w += wgt * v2.w;
    a3.x += wgt * v3.x; a3.y += wgt * v3.y; a3.z += wgt * v3.z; a3.w += wgt * v3.w;
  }

  const float inv = 1.0f / den;  // self-loop guarantees den > 0
  float4* op = reinterpret_cast<float4*>(hout + (size_t)n * HID);
  a0.x *= inv; a0.y *= inv; a0.z *= inv; a0.w *= inv;
  a1.x *= inv; a1.y *= inv; a1.z *= inv; a1.w *= inv;
  a2.x *= inv; a2.y *= inv; a2.z *= inv; a2.w *= inv;
  a3.x *= inv; a3.y *= inv; a3.z *= inv; a3.w *= inv;
  op[0] = a0; op[1] = a1; op[2] = a2; op[3] = a3;
}

// ---------------------------------------------------------------------------
// logits = h @ W2 + b2; out = log_softmax(logits).  One thread per node.
// ---------------------------------------------------------------------------
__global__ void k_out(const float* __restrict__ h, const float* __restrict__ W2,
                      const float* __restrict__ b2, float* __restrict__ out) {
  int n = blockIdx.x * blockDim.x + threadIdx.x;
  if (n >= N_NODES) return;
  const float4* hp = reinterpret_cast<const float4*>(h + (size_t)n * HID);
  const float4 h0 = hp[0], h1 = hp[1], h2 = hp[2], h3 = hp[3];
  const float hv[16] = {h0.x, h0.y, h0.z, h0.w, h1.x, h1.y, h1.z, h1.w,
                        h2.x, h2.y, h2.z, h2.w, h3.x, h3.y, h3.z, h3.w};
  float lg[10];
#pragma unroll
  for (int c = 0; c < NCLS; ++c) {
    float s = b2[c];
#pragma unroll
    for (int j = 0; j < HID; ++j) s = fmaf(hv[j], W2[j * NCLS + c], s);
    lg[c] = s;
  }
  float m = lg[0];
#pragma unroll
  for (int c = 1; c < NCLS; ++c) m = fmaxf(m, lg[c]);
  float se = 0.f;
#pragma unroll
  for (int c = 0; c < NCLS; ++c) se += __expf(lg[c] - m);
  const float ls = m + logf(se);
#pragma unroll
  for (int c = 0; c < NCLS; ++c) out[(size_t)n * NCLS + c] = lg[c] - ls;
}

// ---------------------------------------------------------------------------
extern "C" void kernel_launch(void* const* d_in, const int* in_sizes, int n_in,
                              void* d_out, int out_size, void* d_ws, size_t ws_size,
                              hipStream_t stream) {
  const float* x    = (const float*)d_in[0];
  const int*   ei   = (const int*)d_in[1];
  const float* W1   = (const float*)d_in[2];
  const float* b1   = (const float*)d_in[3];
  const float* beta = (const float*)d_in[4];
  const float* W2   = (const float*)d_in[5];
  const float* b2   = (const float*)d_in[6];
  float* out = (float*)d_out;

  // Workspace layout (floats unless noted).  Total ~34 MB.
  float* hA    = (float*)d_ws;                         // N*16
  float* hB    = hA + (size_t)N_NODES * HID;           // N*16
  float* hn    = hB + (size_t)N_NODES * HID;           // N*16
  float* norms = hn + (size_t)N_NODES * HID;           // N
  int*   offs   = (int*)(norms + N_NODES);             // N+1 (+pad)
  int*   cursor = offs + N_NODES + 8;                  // N
  int*   counts = cursor + N_NODES;                    // N
  int*   bsums  = counts + N_NODES;                    // 256
  int*   csr    = bsums + 256;                         // EPRIME

  hipMemsetAsync(counts, 0, N_NODES * sizeof(int), stream);

  k_gemm_relu<<<1024, 256, 0, stream>>>(x, W1, b1, hA);

  const int ebl = (EPRIME + 255) / 256;
  const int nbScan = (N_NODES + 1023) / 1024;
  k_count<<<ebl, 256, 0, stream>>>(ei, counts);
  k_scan1<<<nbScan, 1024, 0, stream>>>(counts, offs, bsums);
  k_scan2<<<1, 128, 0, stream>>>(bsums, nbScan);
  k_scan3<<<(N_NODES + 255) / 256, 256, 0, stream>>>(offs, bsums, cursor);
  k_fill<<<ebl, 256, 0, stream>>>(ei, cursor, csr);

  const int nbl16 = (N_NODES * HID) / 256;
  const int nbl   = (N_NODES + 255) / 256;

  // conv1 (beta fixed to 1.0)
  k_norm<<<nbl16, 256, 0, stream>>>(hA, hn, norms);
  k_pull<<<nbl, 256, 0, stream>>>(hn, norms, offs, csr, nullptr, hB);

  // conv2 (learnable beta)
  k_norm<<<nbl16, 256, 0, stream>>>(hB, hn, norms);
  k_pull<<<nbl, 256, 0, stream>>>(hn, norms, offs, csr, beta, hA);

  k_out<<<nbl, 256, 0, stream>>>(hA, W2, b2, out);
}

// Round 2
// 329.345 us; speedup vs baseline: 2.0853x; 2.0853x over previous
//
#include <hip/hip_runtime.h>
#include <math.h>

#define N_NODES 100000
#define N_EDGES 3200000
#define EPRIME  (N_EDGES + N_NODES)
#define NFEAT   512
#define HID     16
#define NCLS    10

#define NPB     256                       // nodes per bucket
#define NB      ((N_NODES + NPB - 1) / NPB)   // 391 buckets
#define CHUNK   4096                      // edges per partition workgroup
#define NCHUNKS ((EPRIME + CHUNK - 1) / CHUNK)
#define CAP     12288                     // LDS src capacity in k_csr

// ---------------------------------------------------------------------------
// h = relu(x @ W1 + b1).  One wave per row; W1 (512x16) in registers.
// ---------------------------------------------------------------------------
__global__ __launch_bounds__(256) void k_gemm_relu(const float* __restrict__ x,
                                                   const float* __restrict__ W1,
                                                   const float* __restrict__ b1,
                                                   float* __restrict__ h) {
  const int lane   = threadIdx.x & 63;
  const int wid    = blockIdx.x * (blockDim.x >> 6) + (threadIdx.x >> 6);
  const int nwaves = gridDim.x * (blockDim.x >> 6);

  float4 w[8][4];
#pragma unroll
  for (int kk = 0; kk < 8; ++kk)
#pragma unroll
    for (int j = 0; j < 4; ++j)
      w[kk][j] = *reinterpret_cast<const float4*>(W1 + (lane * 8 + kk) * 16 + j * 4);

  const int outCol = (lane >> 2) & 15;
  const float bias = b1[outCol];

  for (int row = wid; row < N_NODES; row += nwaves) {
    const float4 xv0 = *reinterpret_cast<const float4*>(x + (size_t)row * NFEAT + lane * 8);
    const float4 xv1 = *reinterpret_cast<const float4*>(x + (size_t)row * NFEAT + lane * 8 + 4);
    float xs[8] = {xv0.x, xv0.y, xv0.z, xv0.w, xv1.x, xv1.y, xv1.z, xv1.w};

    float acc[16];
#pragma unroll
    for (int j = 0; j < 16; ++j) acc[j] = 0.f;

#pragma unroll
    for (int kk = 0; kk < 8; ++kk) {
      const float xv = xs[kk];
#pragma unroll
      for (int j4 = 0; j4 < 4; ++j4) {
        acc[j4 * 4 + 0] = fmaf(xv, w[kk][j4].x, acc[j4 * 4 + 0]);
        acc[j4 * 4 + 1] = fmaf(xv, w[kk][j4].y, acc[j4 * 4 + 1]);
        acc[j4 * 4 + 2] = fmaf(xv, w[kk][j4].z, acc[j4 * 4 + 2]);
        acc[j4 * 4 + 3] = fmaf(xv, w[kk][j4].w, acc[j4 * 4 + 3]);
      }
    }

#pragma unroll
    for (int i = 0; i < 8; ++i) {
      float send = (lane & 32) ? acc[i] : acc[i + 8];
      float r = __shfl_xor(send, 32);
      acc[i] = ((lane & 32) ? acc[i + 8] : acc[i]) + r;
    }
#pragma unroll
    for (int i = 0; i < 4; ++i) {
      float send = (lane & 16) ? acc[i] : acc[i + 4];
      float r = __shfl_xor(send, 16);
      acc[i] = ((lane & 16) ? acc[i + 4] : acc[i]) + r;
    }
#pragma unroll
    for (int i = 0; i < 2; ++i) {
      float send = (lane & 8) ? acc[i] : acc[i + 2];
      float r = __shfl_xor(send, 8);
      acc[i] = ((lane & 8) ? acc[i + 2] : acc[i]) + r;
    }
    {
      float send = (lane & 4) ? acc[0] : acc[1];
      float r = __shfl_xor(send, 4);
      acc[0] = ((lane & 4) ? acc[1] : acc[0]) + r;
    }
    acc[0] += __shfl_xor(acc[0], 2);
    acc[0] += __shfl_xor(acc[0], 1);

    if ((lane & 3) == 0)
      h[(size_t)row * HID + outCol] = fmaxf(acc[0] + bias, 0.f);
  }
}

// ---------------------------------------------------------------------------
// CSR build, phase 0: per-bucket edge counts (LDS histogram per chunk).
// ---------------------------------------------------------------------------
__global__ __launch_bounds__(256) void k_bcount(const int* __restrict__ ei,
                                                int* __restrict__ bcnt) {
  __shared__ int hist[NB];
  for (int i = threadIdx.x; i < NB; i += 256) hist[i] = 0;
  __syncthreads();
  const int base = blockIdx.x * CHUNK;
#pragma unroll
  for (int j = 0; j < CHUNK / 256; ++j) {
    int e = base + j * 256 + threadIdx.x;
    if (e < EPRIME) {
      int d = (e < N_EDGES) ? ei[N_EDGES + e] : (e - N_EDGES);
      atomicAdd(&hist[d >> 8], 1);
    }
  }
  __syncthreads();
  for (int i = threadIdx.x; i < NB; i += 256)
    if (hist[i]) atomicAdd(&bcnt[i], hist[i]);
}

// ---------------------------------------------------------------------------
// Phase 0.5: exclusive scan of the 391 bucket counts (single block).
// ---------------------------------------------------------------------------
__global__ void k_bscan(const int* __restrict__ bcnt, int* __restrict__ boffs,
                        int* __restrict__ gcur, int* __restrict__ offs) {
  __shared__ int s[512];
  const int t = threadIdx.x;
  int v = (t < NB) ? bcnt[t] : 0;
  s[t] = v;
  __syncthreads();
  for (int d = 1; d < 512; d <<= 1) {
    int u = (t >= d) ? s[t - d] : 0;
    __syncthreads();
    s[t] += u;
    __syncthreads();
  }
  if (t < NB) {
    int excl = s[t] - v;
    boffs[t] = excl;
    gcur[t] = excl;
  }
  if (t == 0) offs[N_NODES] = EPRIME;
}

// ---------------------------------------------------------------------------
// Phase 1: partition edges into bucket-grouped dense runs of packed u32
// (src | local_dst << 20).  One chunk of 4096 edges per workgroup; LDS
// histogram gives per-edge rank; one global atomic per touched bucket
// reserves a contiguous run, so global writes are dense (no 64B-line
// write amplification).  Static per-thread indexing (no scratch).
// ---------------------------------------------------------------------------
__global__ __launch_bounds__(256) void k_part(const int* __restrict__ ei,
                                              int* __restrict__ gcur,
                                              unsigned int* __restrict__ packed) {
  __shared__ int hist[NB];
  __shared__ int gbase[NB];
  for (int i = threadIdx.x; i < NB; i += 256) hist[i] = 0;
  __syncthreads();

  const int base = blockIdx.x * CHUNK;
  unsigned int pk[CHUNK / 256];
  int bk[CHUNK / 256];
  int rk[CHUNK / 256];
#pragma unroll
  for (int j = 0; j < CHUNK / 256; ++j) {
    int e = base + j * 256 + threadIdx.x;
    bool valid = (e < EPRIME);
    int srcv = 0, d = 0;
    if (valid) {
      if (e < N_EDGES) { srcv = ei[e]; d = ei[N_EDGES + e]; }
      else             { srcv = d = e - N_EDGES; }
    }
    bk[j] = valid ? (d >> 8) : -1;
    pk[j] = (unsigned)srcv | ((unsigned)(d & 255) << 20);
    rk[j] = valid ? atomicAdd(&hist[d >> 8], 1) : 0;
  }
  __syncthreads();

  for (int i = threadIdx.x; i < NB; i += 256) {
    int hc = hist[i];
    gbase[i] = hc ? atomicAdd(&gcur[i], hc) : 0;
  }
  __syncthreads();

#pragma unroll
  for (int j = 0; j < CHUNK / 256; ++j)
    if (bk[j] >= 0) packed[gbase[bk[j]] + rk[j]] = pk[j];
}

// ---------------------------------------------------------------------------
// Phase 2: per-bucket CSR finalize.  One workgroup per bucket: histogram
// local node counts, scan -> per-node offsets (also written to global offs),
// scatter srcs into LDS, dump LDS to csr fully coalesced.
// ---------------------------------------------------------------------------
__global__ __launch_bounds__(256) void k_csr(const unsigned int* __restrict__ packed,
                                             const int* __restrict__ boffs,
                                             const int* __restrict__ bcnt,
                                             int* __restrict__ offs,
                                             int* __restrict__ csr) {
  __shared__ int cnt[NPB];
  __shared__ int cnt2[NPB];
  __shared__ int sc[NPB];
  __shared__ int loffs[NPB];
  __shared__ int srcb[CAP];

  const int b = blockIdx.x;
  const int base = boffs[b];
  const int ne = bcnt[b];
  const int t = threadIdx.x;

  cnt[t] = 0;
  cnt2[t] = 0;
  __syncthreads();

  for (int i = t; i < ne; i += 256) {
    unsigned p = packed[base + i];
    atomicAdd(&cnt[p >> 20], 1);
  }
  __syncthreads();

  // exclusive scan of cnt
  int v = cnt[t];
  sc[t] = v;
  __syncthreads();
  for (int d = 1; d < NPB; d <<= 1) {
    int u = (t >= d) ? sc[t - d] : 0;
    __syncthreads();
    sc[t] += u;
    __syncthreads();
  }
  int excl = sc[t] - v;
  loffs[t] = excl;

  const int node = b * NPB + t;
  if (node < N_NODES) offs[node] = base + excl;
  __syncthreads();

  if (ne <= CAP) {
    for (int i = t; i < ne; i += 256) {
      unsigned p = packed[base + i];
      int local = p >> 20;
      int r = atomicAdd(&cnt2[local], 1);
      srcb[loffs[local] + r] = (int)(p & 0xFFFFF);
    }
    __syncthreads();
    for (int i = t; i < ne; i += 256) csr[base + i] = srcb[i];
  } else {
    for (int i = t; i < ne; i += 256) {
      unsigned p = packed[base + i];
      int local = p >> 20;
      int r = atomicAdd(&cnt2[local], 1);
      csr[base + loffs[local] + r] = (int)(p & 0xFFFFF);
    }
  }
}

// ---------------------------------------------------------------------------
// hn = h / max(||h||, 1e-12); norms[n] = ||h[n]||.  16 lanes per row.
// ---------------------------------------------------------------------------
__global__ void k_norm(const float* __restrict__ h, float* __restrict__ hn,
                       float* __restrict__ norms) {
  int t = blockIdx.x * blockDim.x + threadIdx.x;
  if (t >= N_NODES * HID) return;
  float v = h[t];
  float ss = v * v;
  ss += __shfl_xor(ss, 1);
  ss += __shfl_xor(ss, 2);
  ss += __shfl_xor(ss, 4);
  ss += __shfl_xor(ss, 8);
  float nrm = sqrtf(ss);
  float inv = 1.0f / fmaxf(nrm, 1e-12f);
  hn[t] = v * inv;
  if ((t & 15) == 0) norms[t >> 4] = nrm;
}

// ---------------------------------------------------------------------------
// Pull-mode AGNN conv, 4 lanes per dst node.  Lane q owns features
// [4q,4q+4); the 4 lanes' float4 loads cover exactly the 64B hn[src] line.
// dot reduced with 2 shuffles; denominator replicated per lane.
// ---------------------------------------------------------------------------
__global__ __launch_bounds__(256) void k_pull4(const float* __restrict__ hn,
                                               const float* __restrict__ norms,
                                               const int* __restrict__ offs,
                                               const int* __restrict__ csr,
                                               const float* __restrict__ beta_ptr,
                                               float* __restrict__ hout) {
  const int g = blockIdx.x * blockDim.x + threadIdx.x;
  const int node = g >> 2;
  if (node >= N_NODES) return;
  const int q = g & 3;
  const float beta = beta_ptr ? beta_ptr[0] : 1.0f;

  const float4 qv = *reinterpret_cast<const float4*>(hn + (size_t)node * HID + q * 4);
  const int s = offs[node], e = offs[node + 1];

  float den = 0.f;
  float4 acc = {0.f, 0.f, 0.f, 0.f};

  for (int i = s; i < e; ++i) {
    const int src = csr[i];
    const float4 sv = *reinterpret_cast<const float4*>(hn + (size_t)src * HID + q * 4);
    float pd = qv.x * sv.x + qv.y * sv.y + qv.z * sv.z + qv.w * sv.w;
    pd += __shfl_xor(pd, 1);
    pd += __shfl_xor(pd, 2);
    const float tt = __expf(beta * pd);
    den += tt;
    const float wgt = tt * norms[src];
    acc.x += wgt * sv.x; acc.y += wgt * sv.y; acc.z += wgt * sv.z; acc.w += wgt * sv.w;
  }

  const float inv = 1.0f / den;
  float4* op = reinterpret_cast<float4*>(hout + (size_t)node * HID + q * 4);
  *op = make_float4(acc.x * inv, acc.y * inv, acc.z * inv, acc.w * inv);
}

// ---------------------------------------------------------------------------
// logits = h @ W2 + b2; out = log_softmax(logits).  One thread per node.
// ---------------------------------------------------------------------------
__global__ void k_out(const float* __restrict__ h, const float* __restrict__ W2,
                      const float* __restrict__ b2, float* __restrict__ out) {
  int n = blockIdx.x * blockDim.x + threadIdx.x;
  if (n >= N_NODES) return;
  const float4* hp = reinterpret_cast<const float4*>(h + (size_t)n * HID);
  const float4 h0 = hp[0], h1 = hp[1], h2 = hp[2], h3 = hp[3];
  const float hv[16] = {h0.x, h0.y, h0.z, h0.w, h1.x, h1.y, h1.z, h1.w,
                        h2.x, h2.y, h2.z, h2.w, h3.x, h3.y, h3.z, h3.w};
  float lg[10];
#pragma unroll
  for (int c = 0; c < NCLS; ++c) {
    float s = b2[c];
#pragma unroll
    for (int j = 0; j < HID; ++j) s = fmaf(hv[j], W2[j * NCLS + c], s);
    lg[c] = s;
  }
  float m = lg[0];
#pragma unroll
  for (int c = 1; c < NCLS; ++c) m = fmaxf(m, lg[c]);
  float se = 0.f;
#pragma unroll
  for (int c = 0; c < NCLS; ++c) se += __expf(lg[c] - m);
  const float ls = m + logf(se);
#pragma unroll
  for (int c = 0; c < NCLS; ++c) out[(size_t)n * NCLS + c] = lg[c] - ls;
}

// ---------------------------------------------------------------------------
extern "C" void kernel_launch(void* const* d_in, const int* in_sizes, int n_in,
                              void* d_out, int out_size, void* d_ws, size_t ws_size,
                              hipStream_t stream) {
  const float* x    = (const float*)d_in[0];
  const int*   ei   = (const int*)d_in[1];
  const float* W1   = (const float*)d_in[2];
  const float* b1   = (const float*)d_in[3];
  const float* beta = (const float*)d_in[4];
  const float* W2   = (const float*)d_in[5];
  const float* b2   = (const float*)d_in[6];
  float* out = (float*)d_out;

  // Workspace layout (~33 MB).  packed aliases [hB, hn, norms] exactly
  // (1.6M + 1.6M + 0.1M = 3.3M elements = EPRIME): packed is dead before
  // the first k_norm writes hn/norms and the first k_pull4 writes hB.
  float* hA    = (float*)d_ws;                   // N*16
  float* hB    = hA + (size_t)N_NODES * HID;     // N*16
  float* hn    = hB + (size_t)N_NODES * HID;     // N*16
  float* norms = hn + (size_t)N_NODES * HID;     // N
  int*   offs  = (int*)(norms + N_NODES);        // N+1 (+pad)
  int*   bcnt  = offs + N_NODES + 8;             // NB
  int*   boffs = bcnt + NB;                      // NB
  int*   gcur  = boffs + NB;                     // NB
  int*   csr   = gcur + NB;                      // EPRIME
  unsigned int* packed = (unsigned int*)hB;      // EPRIME (aliased)

  hipMemsetAsync(bcnt, 0, NB * sizeof(int), stream);

  k_gemm_relu<<<1024, 256, 0, stream>>>(x, W1, b1, hA);

  k_bcount<<<NCHUNKS, 256, 0, stream>>>(ei, bcnt);
  k_bscan<<<1, 512, 0, stream>>>(bcnt, boffs, gcur, offs);
  k_part<<<NCHUNKS, 256, 0, stream>>>(ei, gcur, packed);
  k_csr<<<NB, 256, 0, stream>>>(packed, boffs, bcnt, offs, csr);

  const int nbl16 = (N_NODES * HID) / 256;        // 6250
  const int nblP  = (N_NODES * 4 + 255) / 256;    // 1563

  // conv1 (beta fixed to 1.0)
  k_norm<<<nbl16, 256, 0, stream>>>(hA, hn, norms);
  k_pull4<<<nblP, 256, 0, stream>>>(hn, norms, offs, csr, nullptr, hB);

  // conv2 (learnable beta)
  k_norm<<<nbl16, 256, 0, stream>>>(hB, hn, norms);
  k_pull4<<<nblP, 256, 0, stream>>>(hn, norms, offs, csr, beta, hA);

  k_out<<<(N_NODES + 255) / 256, 256, 0, stream>>>(hA, W2, b2, out);
}

// Round 3
// 262.010 us; speedup vs baseline: 2.6212x; 1.2570x over previous
//
#include <hip/hip_runtime.h>
#include <math.h>

#define N_NODES 100000
#define N_EDGES 3200000
#define EPRIME  (N_EDGES + N_NODES)
#define NFEAT   512
#define HID     16
#define NCLS    10

#define NPB     256                           // nodes per bucket
#define NB      ((N_NODES + NPB - 1) / NPB)   // 391 buckets
#define CHUNK   4096                          // edges per partition workgroup
#define NCHUNKS ((EPRIME + CHUNK - 1) / CHUNK)
#define CAPB    10240                         // slot capacity per bucket (~8448 + 20 sigma)
#define CAP     12288                         // LDS src capacity in k_csr

// ---------------------------------------------------------------------------
// hn1 = normalize(relu(x @ W1 + b1)); norms1 = ||relu(...)||.
// One wave per row; W1 (512x16) in registers; next-row prefetch; the
// halving-butterfly reduce leaves each quad holding its column's full sum,
// so the row-norm is a 4-mask butterfly away.  Block 0 also zeroes gcur.
// ---------------------------------------------------------------------------
__global__ __launch_bounds__(256) void k_gemm_norm(const float* __restrict__ x,
                                                   const float* __restrict__ W1,
                                                   const float* __restrict__ b1,
                                                   float* __restrict__ hn1,
                                                   float* __restrict__ norms1,
                                                   int* __restrict__ gcur) {
  if (blockIdx.x == 0)
    for (int i = threadIdx.x; i < NB; i += 256) gcur[i] = 0;

  const int lane   = threadIdx.x & 63;
  const int wid    = blockIdx.x * (blockDim.x >> 6) + (threadIdx.x >> 6);
  const int nwaves = gridDim.x * (blockDim.x >> 6);

  float4 w[8][4];
#pragma unroll
  for (int kk = 0; kk < 8; ++kk)
#pragma unroll
    for (int j = 0; j < 4; ++j)
      w[kk][j] = *reinterpret_cast<const float4*>(W1 + (lane * 8 + kk) * 16 + j * 4);

  const int outCol = (lane >> 2) & 15;
  const float bias = b1[outCol];

  float4 n0, n1;
  if (wid < N_NODES) {
    n0 = *reinterpret_cast<const float4*>(x + (size_t)wid * NFEAT + lane * 8);
    n1 = *reinterpret_cast<const float4*>(x + (size_t)wid * NFEAT + lane * 8 + 4);
  }

  for (int row = wid; row < N_NODES; row += nwaves) {
    const float4 c0 = n0, c1 = n1;
    const int nr = row + nwaves;
    if (nr < N_NODES) {
      n0 = *reinterpret_cast<const float4*>(x + (size_t)nr * NFEAT + lane * 8);
      n1 = *reinterpret_cast<const float4*>(x + (size_t)nr * NFEAT + lane * 8 + 4);
    }
    float xs[8] = {c0.x, c0.y, c0.z, c0.w, c1.x, c1.y, c1.z, c1.w};

    float acc[16];
#pragma unroll
    for (int j = 0; j < 16; ++j) acc[j] = 0.f;

#pragma unroll
    for (int kk = 0; kk < 8; ++kk) {
      const float xv = xs[kk];
#pragma unroll
      for (int j4 = 0; j4 < 4; ++j4) {
        acc[j4 * 4 + 0] = fmaf(xv, w[kk][j4].x, acc[j4 * 4 + 0]);
        acc[j4 * 4 + 1] = fmaf(xv, w[kk][j4].y, acc[j4 * 4 + 1]);
        acc[j4 * 4 + 2] = fmaf(xv, w[kk][j4].z, acc[j4 * 4 + 2]);
        acc[j4 * 4 + 3] = fmaf(xv, w[kk][j4].w, acc[j4 * 4 + 3]);
      }
    }

#pragma unroll
    for (int i = 0; i < 8; ++i) {
      float send = (lane & 32) ? acc[i] : acc[i + 8];
      float r = __shfl_xor(send, 32);
      acc[i] = ((lane & 32) ? acc[i + 8] : acc[i]) + r;
    }
#pragma unroll
    for (int i = 0; i < 4; ++i) {
      float send = (lane & 16) ? acc[i] : acc[i + 4];
      float r = __shfl_xor(send, 16);
      acc[i] = ((lane & 16) ? acc[i + 4] : acc[i]) + r;
    }
#pragma unroll
    for (int i = 0; i < 2; ++i) {
      float send = (lane & 8) ? acc[i] : acc[i + 2];
      float r = __shfl_xor(send, 8);
      acc[i] = ((lane & 8) ? acc[i + 2] : acc[i]) + r;
    }
    {
      float send = (lane & 4) ? acc[0] : acc[1];
      float r = __shfl_xor(send, 4);
      acc[0] = ((lane & 4) ? acc[1] : acc[0]) + r;
    }
    acc[0] += __shfl_xor(acc[0], 2);
    acc[0] += __shfl_xor(acc[0], 1);
    // now every lane holds the full column sum for col (lane>>2)&15,
    // uniform within each quad.

    const float v = fmaxf(acc[0] + bias, 0.f);
    float ss = v * v;
    ss += __shfl_xor(ss, 4);
    ss += __shfl_xor(ss, 8);
    ss += __shfl_xor(ss, 16);
    ss += __shfl_xor(ss, 32);
    const float nrm = sqrtf(ss);
    const float inv = 1.0f / fmaxf(nrm, 1e-12f);

    if ((lane & 3) == 0) {
      hn1[(size_t)row * HID + outCol] = v * inv;
      if (lane == 0) norms1[row] = nrm;
    }
  }
}

// ---------------------------------------------------------------------------
// Partition edges into per-bucket slot areas of packed u32 (src | ldst<<20).
// One chunk of 4096 edges per workgroup; LDS histogram gives per-edge rank;
// one global atomic per touched bucket reserves a contiguous run.
// ---------------------------------------------------------------------------
__global__ __launch_bounds__(256) void k_part(const int* __restrict__ ei,
                                              int* __restrict__ gcur,
                                              unsigned int* __restrict__ slots) {
  __shared__ int hist[NB];
  __shared__ int gbase[NB];
  for (int i = threadIdx.x; i < NB; i += 256) hist[i] = 0;
  __syncthreads();

  const int base = blockIdx.x * CHUNK;
  unsigned int pk[CHUNK / 256];
  int bk[CHUNK / 256];
  int rk[CHUNK / 256];
#pragma unroll
  for (int j = 0; j < CHUNK / 256; ++j) {
    int e = base + j * 256 + threadIdx.x;
    bool valid = (e < EPRIME);
    int srcv = 0, d = 0;
    if (valid) {
      if (e < N_EDGES) { srcv = ei[e]; d = ei[N_EDGES + e]; }
      else             { srcv = d = e - N_EDGES; }
    }
    bk[j] = valid ? (d >> 8) : -1;
    pk[j] = (unsigned)srcv | ((unsigned)(d & 255) << 20);
    rk[j] = valid ? atomicAdd(&hist[d >> 8], 1) : 0;
  }
  __syncthreads();

  for (int i = threadIdx.x; i < NB; i += 256) {
    int hc = hist[i];
    gbase[i] = hc ? atomicAdd(&gcur[i], hc) : 0;
  }
  __syncthreads();

#pragma unroll
  for (int j = 0; j < CHUNK / 256; ++j)
    if (bk[j] >= 0) slots[(size_t)bk[j] * CAPB + gbase[bk[j]] + rk[j]] = pk[j];
}

// ---------------------------------------------------------------------------
// Exclusive scan of the 391 bucket counts; also offs[N]=EPRIME and csr pad.
// ---------------------------------------------------------------------------
__global__ void k_bscan(const int* __restrict__ gcur, int* __restrict__ boffs,
                        int* __restrict__ offs, int* __restrict__ csr) {
  __shared__ int s[512];
  const int t = threadIdx.x;
  int v = (t < NB) ? gcur[t] : 0;
  s[t] = v;
  __syncthreads();
  for (int d = 1; d < 512; d <<= 1) {
    int u = (t >= d) ? s[t - d] : 0;
    __syncthreads();
    s[t] += u;
    __syncthreads();
  }
  if (t < NB) boffs[t] = s[t] - v;
  if (t == 0) offs[N_NODES] = EPRIME;
  if (t >= 480 && t < 496) csr[EPRIME + (t - 480)] = 0;  // pad for pull over-read
}

// ---------------------------------------------------------------------------
// Per-bucket CSR finalize: histogram local node counts, scan -> offsets,
// scatter srcs into LDS, dump coalesced.
// ---------------------------------------------------------------------------
__global__ __launch_bounds__(256) void k_csr(const unsigned int* __restrict__ slots,
                                             const int* __restrict__ boffs,
                                             const int* __restrict__ gcur,
                                             int* __restrict__ offs,
                                             int* __restrict__ csr) {
  __shared__ int cnt[NPB];
  __shared__ int cnt2[NPB];
  __shared__ int sc[NPB];
  __shared__ int loffs[NPB];
  __shared__ int srcb[CAP];

  const int b = blockIdx.x;
  const int base = boffs[b];
  const int ne = gcur[b];
  const int t = threadIdx.x;
  const unsigned int* my = slots + (size_t)b * CAPB;

  cnt[t] = 0;
  cnt2[t] = 0;
  __syncthreads();

  for (int i = t; i < ne; i += 256) atomicAdd(&cnt[my[i] >> 20], 1);
  __syncthreads();

  int v = cnt[t];
  sc[t] = v;
  __syncthreads();
  for (int d = 1; d < NPB; d <<= 1) {
    int u = (t >= d) ? sc[t - d] : 0;
    __syncthreads();
    sc[t] += u;
    __syncthreads();
  }
  int excl = sc[t] - v;
  loffs[t] = excl;

  const int node = b * NPB + t;
  if (node < N_NODES) offs[node] = base + excl;
  __syncthreads();

  if (ne <= CAP) {
    for (int i = t; i < ne; i += 256) {
      unsigned p = my[i];
      int local = p >> 20;
      int r = atomicAdd(&cnt2[local], 1);
      srcb[loffs[local] + r] = (int)(p & 0xFFFFF);
    }
    __syncthreads();
    for (int i = t; i < ne; i += 256) csr[base + i] = srcb[i];
  } else {
    for (int i = t; i < ne; i += 256) {
      unsigned p = my[i];
      int local = p >> 20;
      int r = atomicAdd(&cnt2[local], 1);
      csr[base + loffs[local] + r] = (int)(p & 0xFFFFF);
    }
  }
}

// ---------------------------------------------------------------------------
// Pull-mode AGNN conv, one WAVE per dst node: 16 edge slots x 4 feature
// lanes.  Per iteration the wave has 16 independent 64B hn-line gathers in
// flight.  NORM=true fuses the next layer's L2-normalize into the epilogue.
// ---------------------------------------------------------------------------
template <bool NORM>
__global__ __launch_bounds__(256) void k_pull(const float* __restrict__ hn,
                                              const float* __restrict__ norms,
                                              const int* __restrict__ offs,
                                              const int* __restrict__ csr,
                                              const float* __restrict__ beta_ptr,
                                              float* __restrict__ outv,
                                              float* __restrict__ out_norms) {
  const int node = blockIdx.x * (blockDim.x >> 6) + (threadIdx.x >> 6);
  if (node >= N_NODES) return;
  const int lane = threadIdx.x & 63;
  const int q    = lane & 3;   // feature quad: floats [4q, 4q+4)
  const int slot = lane >> 2;  // edge slot 0..15
  const float beta = beta_ptr ? beta_ptr[0] : 1.0f;

  const float4 qv = *reinterpret_cast<const float4*>(hn + (size_t)node * HID + q * 4);
  const int s = offs[node], e = offs[node + 1];

  float den = 0.f;
  float4 acc = {0.f, 0.f, 0.f, 0.f};

  for (int base = s; base < e; base += 16) {
    const int i = base + slot;
    const int src = csr[i];  // over-read lands in next node's edges or the pad
    const float4 sv = *reinterpret_cast<const float4*>(hn + (size_t)src * HID + q * 4);
    float pd = qv.x * sv.x + qv.y * sv.y + qv.z * sv.z + qv.w * sv.w;
    pd += __shfl_xor(pd, 1);
    pd += __shfl_xor(pd, 2);
    const float t = (i < e) ? __expf(beta * pd) : 0.f;
    den += t;
    const float wgt = t * norms[src];
    acc.x += wgt * sv.x; acc.y += wgt * sv.y; acc.z += wgt * sv.z; acc.w += wgt * sv.w;
  }

  // reduce across the 16 slots (lanes with equal lane&3)
#pragma unroll
  for (int m = 4; m <= 32; m <<= 1) {
    den   += __shfl_xor(den, m);
    acc.x += __shfl_xor(acc.x, m);
    acc.y += __shfl_xor(acc.y, m);
    acc.z += __shfl_xor(acc.z, m);
    acc.w += __shfl_xor(acc.w, m);
  }
  const float inv = 1.0f / den;  // self-loop guarantees den > 0
  acc.x *= inv; acc.y *= inv; acc.z *= inv; acc.w *= inv;

  if (NORM) {
    float ss = acc.x * acc.x + acc.y * acc.y + acc.z * acc.z + acc.w * acc.w;
    ss += __shfl_xor(ss, 1);
    ss += __shfl_xor(ss, 2);
    const float nrm = sqrtf(ss);
    const float ninv = 1.0f / fmaxf(nrm, 1e-12f);
    if (lane < 4) {
      *reinterpret_cast<float4*>(outv + (size_t)node * HID + q * 4) =
          make_float4(acc.x * ninv, acc.y * ninv, acc.z * ninv, acc.w * ninv);
      if (lane == 0) out_norms[node] = nrm;
    }
  } else {
    if (lane < 4)
      *reinterpret_cast<float4*>(outv + (size_t)node * HID + q * 4) = acc;
  }
}

// ---------------------------------------------------------------------------
// logits = h @ W2 + b2; out = log_softmax(logits).  One thread per node.
// ---------------------------------------------------------------------------
__global__ void k_out(const float* __restrict__ h, const float* __restrict__ W2,
                      const float* __restrict__ b2, float* __restrict__ out) {
  int n = blockIdx.x * blockDim.x + threadIdx.x;
  if (n >= N_NODES) return;
  const float4* hp = reinterpret_cast<const float4*>(h + (size_t)n * HID);
  const float4 h0 = hp[0], h1 = hp[1], h2 = hp[2], h3 = hp[3];
  const float hv[16] = {h0.x, h0.y, h0.z, h0.w, h1.x, h1.y, h1.z, h1.w,
                        h2.x, h2.y, h2.z, h2.w, h3.x, h3.y, h3.z, h3.w};
  float lg[10];
#pragma unroll
  for (int c = 0; c < NCLS; ++c) {
    float s = b2[c];
#pragma unroll
    for (int j = 0; j < HID; ++j) s = fmaf(hv[j], W2[j * NCLS + c], s);
    lg[c] = s;
  }
  float m = lg[0];
#pragma unroll
  for (int c = 1; c < NCLS; ++c) m = fmaxf(m, lg[c]);
  float se = 0.f;
#pragma unroll
  for (int c = 0; c < NCLS; ++c) se += __expf(lg[c] - m);
  const float ls = m + logf(se);
#pragma unroll
  for (int c = 0; c < NCLS; ++c) out[(size_t)n * NCLS + c] = lg[c] - ls;
}

// ---------------------------------------------------------------------------
extern "C" void kernel_launch(void* const* d_in, const int* in_sizes, int n_in,
                              void* d_out, int out_size, void* d_ws, size_t ws_size,
                              hipStream_t stream) {
  const float* x    = (const float*)d_in[0];
  const int*   ei   = (const int*)d_in[1];
  const float* W1   = (const float*)d_in[2];
  const float* b1   = (const float*)d_in[3];
  const float* beta = (const float*)d_in[4];
  const float* W2   = (const float*)d_in[5];
  const float* b2   = (const float*)d_in[6];
  float* out = (float*)d_out;

  // Workspace layout (~50 MB), all distinct.
  float* hn1    = (float*)d_ws;                    // N*16
  float* norms1 = hn1 + (size_t)N_NODES * HID;     // N
  float* hn2    = norms1 + N_NODES;                // N*16
  float* norms2 = hn2 + (size_t)N_NODES * HID;     // N
  float* h3     = norms2 + N_NODES;                // N*16
  int*   offs   = (int*)(h3 + (size_t)N_NODES * HID); // N+1 (+pad)
  int*   gcur   = offs + N_NODES + 8;              // NB
  int*   boffs  = gcur + NB;                       // NB
  int*   csr    = boffs + NB;                      // EPRIME + 16 pad
  unsigned int* slots = (unsigned int*)(csr + EPRIME + 16);  // NB*CAPB

  k_gemm_norm<<<1024, 256, 0, stream>>>(x, W1, b1, hn1, norms1, gcur);

  k_part<<<NCHUNKS, 256, 0, stream>>>(ei, gcur, slots);
  k_bscan<<<1, 512, 0, stream>>>(gcur, boffs, offs, csr);
  k_csr<<<NB, 256, 0, stream>>>(slots, boffs, gcur, offs, csr);

  const int nblW = (N_NODES * 64 + 255) / 256;  // one wave per node

  k_pull<true><<<nblW, 256, 0, stream>>>(hn1, norms1, offs, csr, nullptr, hn2, norms2);
  k_pull<false><<<nblW, 256, 0, stream>>>(hn2, norms2, offs, csr, beta, h3, nullptr);

  k_out<<<(N_NODES + 255) / 256, 256, 0, stream>>>(h3, W2, b2, out);
}

// Round 4
// 257.997 us; speedup vs baseline: 2.6619x; 1.0156x over previous
//
#include <hip/hip_runtime.h>
#include <hip/hip_fp16.h>
#include <math.h>

#define N_NODES 100000
#define N_EDGES 3200000
#define EPRIME  (N_EDGES + N_NODES)
#define NFEAT   512
#define HID     16
#define NCLS    10

#define NPB     256                           // nodes per bucket
#define NB      ((N_NODES + NPB - 1) / NPB)   // 391 buckets
#define CHUNK   4096                          // edges per partition workgroup
#define NCHUNKS ((EPRIME + CHUNK - 1) / CHUNK)
#define CAPB    10240                         // slot capacity per bucket (~8448 + 20 sigma)
#define CAP     12288                         // LDS src capacity in k_csr

union U2 { unsigned int u; __half2 h; };
__device__ __forceinline__ float2 u2f(unsigned int v) {
  U2 t; t.u = v; return __half22float2(t.h);
}

// ---------------------------------------------------------------------------
// hn1 = fp16(normalize(relu(x @ W1 + b1))); norms1 = ||relu(...)||.
// One wave per row; W1 (512x16) in registers; prefetch depth 2 (three row
// buffers) so ~4KB/wave of HBM loads stay in flight.  Block 0 zeroes gcur.
// ---------------------------------------------------------------------------
__global__ __launch_bounds__(256) void k_gemm_norm(const float* __restrict__ x,
                                                   const float* __restrict__ W1,
                                                   const float* __restrict__ b1,
                                                   __half* __restrict__ hn1,
                                                   float* __restrict__ norms1,
                                                   int* __restrict__ gcur) {
  if (blockIdx.x == 0)
    for (int i = threadIdx.x; i < NB; i += 256) gcur[i] = 0;

  const int lane = threadIdx.x & 63;
  const int wid  = blockIdx.x * 4 + (threadIdx.x >> 6);
  const int nw   = gridDim.x * 4;

  float4 w[8][4];
#pragma unroll
  for (int kk = 0; kk < 8; ++kk)
#pragma unroll
    for (int j = 0; j < 4; ++j)
      w[kk][j] = *reinterpret_cast<const float4*>(W1 + (lane * 8 + kk) * 16 + j * 4);

  const int outCol = (lane >> 2) & 15;
  const float bias = b1[outCol];

  const float4 z4 = make_float4(0.f, 0.f, 0.f, 0.f);
  float4 c0 = z4, c1 = z4, p0 = z4, p1 = z4, t0 = z4, t1 = z4;

  if (wid < N_NODES) {
    c0 = *reinterpret_cast<const float4*>(x + (size_t)wid * NFEAT + lane * 8);
    c1 = *reinterpret_cast<const float4*>(x + (size_t)wid * NFEAT + lane * 8 + 4);
  }
  if (wid + nw < N_NODES) {
    p0 = *reinterpret_cast<const float4*>(x + (size_t)(wid + nw) * NFEAT + lane * 8);
    p1 = *reinterpret_cast<const float4*>(x + (size_t)(wid + nw) * NFEAT + lane * 8 + 4);
  }

  for (int row = wid; row < N_NODES; row += nw) {
    const int r2 = row + 2 * nw;
    if (r2 < N_NODES) {
      t0 = *reinterpret_cast<const float4*>(x + (size_t)r2 * NFEAT + lane * 8);
      t1 = *reinterpret_cast<const float4*>(x + (size_t)r2 * NFEAT + lane * 8 + 4);
    }

    float xs[8] = {c0.x, c0.y, c0.z, c0.w, c1.x, c1.y, c1.z, c1.w};

    float acc[16];
#pragma unroll
    for (int j = 0; j < 16; ++j) acc[j] = 0.f;

#pragma unroll
    for (int kk = 0; kk < 8; ++kk) {
      const float xv = xs[kk];
#pragma unroll
      for (int j4 = 0; j4 < 4; ++j4) {
        acc[j4 * 4 + 0] = fmaf(xv, w[kk][j4].x, acc[j4 * 4 + 0]);
        acc[j4 * 4 + 1] = fmaf(xv, w[kk][j4].y, acc[j4 * 4 + 1]);
        acc[j4 * 4 + 2] = fmaf(xv, w[kk][j4].z, acc[j4 * 4 + 2]);
        acc[j4 * 4 + 3] = fmaf(xv, w[kk][j4].w, acc[j4 * 4 + 3]);
      }
    }

#pragma unroll
    for (int i = 0; i < 8; ++i) {
      float send = (lane & 32) ? acc[i] : acc[i + 8];
      float r = __shfl_xor(send, 32);
      acc[i] = ((lane & 32) ? acc[i + 8] : acc[i]) + r;
    }
#pragma unroll
    for (int i = 0; i < 4; ++i) {
      float send = (lane & 16) ? acc[i] : acc[i + 4];
      float r = __shfl_xor(send, 16);
      acc[i] = ((lane & 16) ? acc[i + 4] : acc[i]) + r;
    }
#pragma unroll
    for (int i = 0; i < 2; ++i) {
      float send = (lane & 8) ? acc[i] : acc[i + 2];
      float r = __shfl_xor(send, 8);
      acc[i] = ((lane & 8) ? acc[i + 2] : acc[i]) + r;
    }
    {
      float send = (lane & 4) ? acc[0] : acc[1];
      float r = __shfl_xor(send, 4);
      acc[0] = ((lane & 4) ? acc[1] : acc[0]) + r;
    }
    acc[0] += __shfl_xor(acc[0], 2);
    acc[0] += __shfl_xor(acc[0], 1);
    // every lane now holds the full column sum for col (lane>>2)&15.

    const float v = fmaxf(acc[0] + bias, 0.f);
    float ss = v * v;
    ss += __shfl_xor(ss, 4);
    ss += __shfl_xor(ss, 8);
    ss += __shfl_xor(ss, 16);
    ss += __shfl_xor(ss, 32);
    const float nrm = sqrtf(ss);
    const float vs = v / fmaxf(nrm, 1e-12f);

    // writer lane w (0..15) pulls col w's value from lane 4w, writes fp16.
    const float wv = __shfl(vs, (lane & 15) * 4);
    if (lane < 16) hn1[(size_t)row * HID + lane] = __float2half_rn(wv);
    if (lane == 0) norms1[row] = nrm;

    c0 = p0; c1 = p1; p0 = t0; p1 = t1;
  }
}

// ---------------------------------------------------------------------------
// Partition edges into per-bucket slot areas of packed u32 (src | ldst<<20).
// ---------------------------------------------------------------------------
__global__ __launch_bounds__(256) void k_part(const int* __restrict__ ei,
                                              int* __restrict__ gcur,
                                              unsigned int* __restrict__ slots) {
  __shared__ int hist[NB];
  __shared__ int gbase[NB];
  for (int i = threadIdx.x; i < NB; i += 256) hist[i] = 0;
  __syncthreads();

  const int base = blockIdx.x * CHUNK;
  unsigned int pk[CHUNK / 256];
  int bk[CHUNK / 256];
  int rk[CHUNK / 256];
#pragma unroll
  for (int j = 0; j < CHUNK / 256; ++j) {
    int e = base + j * 256 + threadIdx.x;
    bool valid = (e < EPRIME);
    int srcv = 0, d = 0;
    if (valid) {
      if (e < N_EDGES) { srcv = ei[e]; d = ei[N_EDGES + e]; }
      else             { srcv = d = e - N_EDGES; }
    }
    bk[j] = valid ? (d >> 8) : -1;
    pk[j] = (unsigned)srcv | ((unsigned)(d & 255) << 20);
    rk[j] = valid ? atomicAdd(&hist[d >> 8], 1) : 0;
  }
  __syncthreads();

  for (int i = threadIdx.x; i < NB; i += 256) {
    int hc = hist[i];
    gbase[i] = hc ? atomicAdd(&gcur[i], hc) : 0;
  }
  __syncthreads();

#pragma unroll
  for (int j = 0; j < CHUNK / 256; ++j)
    if (bk[j] >= 0) slots[(size_t)bk[j] * CAPB + gbase[bk[j]] + rk[j]] = pk[j];
}

// ---------------------------------------------------------------------------
// Exclusive scan of the 391 bucket counts; offs[N]=EPRIME; csr tail pad.
// ---------------------------------------------------------------------------
__global__ void k_bscan(const int* __restrict__ gcur, int* __restrict__ boffs,
                        int* __restrict__ offs, int* __restrict__ csr) {
  __shared__ int s[512];
  const int t = threadIdx.x;
  int v = (t < NB) ? gcur[t] : 0;
  s[t] = v;
  __syncthreads();
  for (int d = 1; d < 512; d <<= 1) {
    int u = (t >= d) ? s[t - d] : 0;
    __syncthreads();
    s[t] += u;
    __syncthreads();
  }
  if (t < NB) boffs[t] = s[t] - v;
  if (t == 0) offs[N_NODES] = EPRIME;
  if (t >= 480 && t < 496) csr[EPRIME + (t - 480)] = 0;  // pad for pull over-read
}

// ---------------------------------------------------------------------------
// Per-bucket CSR finalize: histogram local node counts, scan -> offsets,
// scatter srcs into LDS, dump coalesced.
// ---------------------------------------------------------------------------
__global__ __launch_bounds__(256) void k_csr(const unsigned int* __restrict__ slots,
                                             const int* __restrict__ boffs,
                                             const int* __restrict__ gcur,
                                             int* __restrict__ offs,
                                             int* __restrict__ csr) {
  __shared__ int cnt[NPB];
  __shared__ int cnt2[NPB];
  __shared__ int sc[NPB];
  __shared__ int loffs[NPB];
  __shared__ int srcb[CAP];

  const int b = blockIdx.x;
  const int base = boffs[b];
  const int ne = gcur[b];
  const int t = threadIdx.x;
  const unsigned int* my = slots + (size_t)b * CAPB;

  cnt[t] = 0;
  cnt2[t] = 0;
  __syncthreads();

  for (int i = t; i < ne; i += 256) atomicAdd(&cnt[my[i] >> 20], 1);
  __syncthreads();

  int v = cnt[t];
  sc[t] = v;
  __syncthreads();
  for (int d = 1; d < NPB; d <<= 1) {
    int u = (t >= d) ? sc[t - d] : 0;
    __syncthreads();
    sc[t] += u;
    __syncthreads();
  }
  int excl = sc[t] - v;
  loffs[t] = excl;

  const int node = b * NPB + t;
  if (node < N_NODES) offs[node] = base + excl;
  __syncthreads();

  if (ne <= CAP) {
    for (int i = t; i < ne; i += 256) {
      unsigned p = my[i];
      int local = p >> 20;
      int r = atomicAdd(&cnt2[local], 1);
      srcb[loffs[local] + r] = (int)(p & 0xFFFFF);
    }
    __syncthreads();
    for (int i = t; i < ne; i += 256) csr[base + i] = srcb[i];
  } else {
    for (int i = t; i < ne; i += 256) {
      unsigned p = my[i];
      int local = p >> 20;
      int r = atomicAdd(&cnt2[local], 1);
      csr[base + loffs[local] + r] = (int)(p & 0xFFFFF);
    }
  }
}

// ---------------------------------------------------------------------------
// Pull-mode AGNN conv, one WAVE per dst node: 16 edge slots x 4 feature
// lanes.  hn is fp16 (32B rows -> whole array is 3.2MB, L2-resident per
// XCD); accumulation fp32.  FINAL=false fuses the next layer's normalize
// (fp16 out + norm); FINAL=true writes fp32 h3 for k_out.
// ---------------------------------------------------------------------------
template <bool FINAL>
__global__ __launch_bounds__(256) void k_pull(const __half* __restrict__ hn,
                                              const float* __restrict__ norms,
                                              const int* __restrict__ offs,
                                              const int* __restrict__ csr,
                                              const float* __restrict__ beta_ptr,
                                              __half* __restrict__ out_hn,
                                              float* __restrict__ out_norms,
                                              float* __restrict__ h3) {
  const int node = blockIdx.x * 4 + (threadIdx.x >> 6);
  if (node >= N_NODES) return;
  const int lane = threadIdx.x & 63;
  const int q    = lane & 3;   // feature quad: floats [4q, 4q+4)
  const int slot = lane >> 2;  // edge slot 0..15
  const float beta = FINAL ? beta_ptr[0] : 1.0f;

  const uint2 qraw = *reinterpret_cast<const uint2*>(hn + (size_t)node * HID + q * 4);
  const float2 qa = u2f(qraw.x), qb = u2f(qraw.y);
  const int s = offs[node], e = offs[node + 1];

  float den = 0.f;
  float ax = 0.f, ay = 0.f, az = 0.f, aw = 0.f;

  for (int b2 = s; b2 < e; b2 += 16) {
    const int i = b2 + slot;
    const int src = csr[i];  // over-read lands in next node's edges or the pad
    const uint2 r = *reinterpret_cast<const uint2*>(hn + (size_t)src * HID + q * 4);
    const float2 f0 = u2f(r.x), f1 = u2f(r.y);
    float pd = qa.x * f0.x + qa.y * f0.y + qb.x * f1.x + qb.y * f1.y;
    pd += __shfl_xor(pd, 1);
    pd += __shfl_xor(pd, 2);
    const float t = (i < e) ? __expf(beta * pd) : 0.f;
    den += t;
    const float wgt = t * norms[src];
    ax += wgt * f0.x; ay += wgt * f0.y; az += wgt * f1.x; aw += wgt * f1.y;
  }

  // reduce across the 16 slots (lanes with equal lane&3)
#pragma unroll
  for (int m = 4; m <= 32; m <<= 1) {
    den += __shfl_xor(den, m);
    ax  += __shfl_xor(ax, m);
    ay  += __shfl_xor(ay, m);
    az  += __shfl_xor(az, m);
    aw  += __shfl_xor(aw, m);
  }
  const float inv = 1.0f / den;  // self-loop guarantees den > 0
  ax *= inv; ay *= inv; az *= inv; aw *= inv;

  if (!FINAL) {
    float ssn = ax * ax + ay * ay + az * az + aw * aw;
    ssn += __shfl_xor(ssn, 1);
    ssn += __shfl_xor(ssn, 2);
    const float nrm = sqrtf(ssn);
    const float ninv = 1.0f / fmaxf(nrm, 1e-12f);
    if (lane < 4) {
      U2 lo, hi;
      lo.h = __floats2half2_rn(ax * ninv, ay * ninv);
      hi.h = __floats2half2_rn(az * ninv, aw * ninv);
      *reinterpret_cast<uint2*>(out_hn + (size_t)node * HID + q * 4) =
          make_uint2(lo.u, hi.u);
      if (lane == 0) out_norms[node] = nrm;
    }
  } else {
    if (lane < 4)
      *reinterpret_cast<float4*>(h3 + (size_t)node * HID + q * 4) =
          make_float4(ax, ay, az, aw);
  }
}

// ---------------------------------------------------------------------------
// logits = h @ W2 + b2; out = log_softmax(logits).  One thread per node.
// ---------------------------------------------------------------------------
__global__ void k_out(const float* __restrict__ h, const float* __restrict__ W2,
                      const float* __restrict__ b2, float* __restrict__ out) {
  int n = blockIdx.x * blockDim.x + threadIdx.x;
  if (n >= N_NODES) return;
  const float4* hp = reinterpret_cast<const float4*>(h + (size_t)n * HID);
  const float4 h0 = hp[0], h1 = hp[1], h2 = hp[2], h3 = hp[3];
  const float hv[16] = {h0.x, h0.y, h0.z, h0.w, h1.x, h1.y, h1.z, h1.w,
                        h2.x, h2.y, h2.z, h2.w, h3.x, h3.y, h3.z, h3.w};
  float lg[10];
#pragma unroll
  for (int c = 0; c < NCLS; ++c) {
    float s = b2[c];
#pragma unroll
    for (int j = 0; j < HID; ++j) s = fmaf(hv[j], W2[j * NCLS + c], s);
    lg[c] = s;
  }
  float m = lg[0];
#pragma unroll
  for (int c = 1; c < NCLS; ++c) m = fmaxf(m, lg[c]);
  float se = 0.f;
#pragma unroll
  for (int c = 0; c < NCLS; ++c) se += __expf(lg[c] - m);
  const float ls = m + logf(se);
#pragma unroll
  for (int c = 0; c < NCLS; ++c) out[(size_t)n * NCLS + c] = lg[c] - ls;
}

// ---------------------------------------------------------------------------
extern "C" void kernel_launch(void* const* d_in, const int* in_sizes, int n_in,
                              void* d_out, int out_size, void* d_ws, size_t ws_size,
                              hipStream_t stream) {
  const float* x    = (const float*)d_in[0];
  const int*   ei   = (const int*)d_in[1];
  const float* W1   = (const float*)d_in[2];
  const float* b1   = (const float*)d_in[3];
  const float* beta = (const float*)d_in[4];
  const float* W2   = (const float*)d_in[5];
  const float* b2   = (const float*)d_in[6];
  float* out = (float*)d_out;

  // Workspace layout (~43 MB); all float-offset counts are even, so every
  // half-array stays 8B-aligned and h3 16B-aligned.
  float*  base   = (float*)d_ws;
  __half* hn1    = (__half*)base;                          // N*16 half = N*8 f
  float*  norms1 = base + (size_t)N_NODES * 8;             // N
  __half* hn2    = (__half*)(norms1 + N_NODES);            // N*16 half
  float*  norms2 = (float*)(hn2 + (size_t)N_NODES * HID);  // N
  float*  h3     = norms2 + N_NODES;                       // N*16
  int*    offs   = (int*)(h3 + (size_t)N_NODES * HID);     // N+1 (+pad)
  int*    gcur   = offs + N_NODES + 8;                     // NB
  int*    boffs  = gcur + NB;                              // NB
  int*    csr    = boffs + NB;                             // EPRIME + 16 pad
  unsigned int* slots = (unsigned int*)(csr + EPRIME + 16);  // NB*CAPB

  k_gemm_norm<<<1024, 256, 0, stream>>>(x, W1, b1, hn1, norms1, gcur);

  k_part<<<NCHUNKS, 256, 0, stream>>>(ei, gcur, slots);
  k_bscan<<<1, 512, 0, stream>>>(gcur, boffs, offs, csr);
  k_csr<<<NB, 256, 0, stream>>>(slots, boffs, gcur, offs, csr);

  const int nblW = (N_NODES + 3) / 4;  // one wave per node, 4 waves/block

  k_pull<false><<<nblW, 256, 0, stream>>>(hn1, norms1, offs, csr, nullptr,
                                          hn2, norms2, nullptr);
  k_pull<true><<<nblW, 256, 0, stream>>>(hn2, norms2, offs, csr, beta,
                                         nullptr, nullptr, h3);

  k_out<<<(N_NODES + 255) / 256, 256, 0, stream>>>(h3, W2, b2, out);
}